// Round 1
// baseline (134.158 us; speedup 1.0000x reference)
//
#include <hip/hip_runtime.h>

// Problem constants (fixed by the reference file).
#define T_LEN 8192
#define D_CH  2048
#define C_CHUNKS 64
#define L_CHUNK  (T_LEN / C_CHUNKS)   // 128

// v = z*v + x   (x real), z complex. Two independent 2-deep FMA chains.
__device__ __forceinline__ void step_real(float zre, float zim,
                                          float& vre, float& vim, float x) {
    float nre = fmaf(zre, vre, fmaf(-zim, vim, x));
    float nim = fmaf(zre, vim, zim * vre);
    vre = nre; vim = nim;
}

__device__ __forceinline__ void load_z(const float* __restrict__ size_,
                                       const float* __restrict__ theta_,
                                       int d, float& zre, float& zim) {
    float e = expf(size_[d]);
    float r = expf(-e);
    float s, c;
    sincosf(theta_[d], &s, &c);
    zre = r * c;
    zim = r * s;
}

// Pass 1: per (chunk, channel) local scan from v=0; write chunk-final value.
__global__ __launch_bounds__(256) void k_local(const float* __restrict__ x,
                                               const float* __restrict__ size_,
                                               const float* __restrict__ theta_,
                                               float2* __restrict__ b) {
    const int d = blockIdx.x * 256 + threadIdx.x;
    const int c = blockIdx.y;
    float zre, zim;
    load_z(size_, theta_, d, zre, zim);

    const float* xp = x + (size_t)c * L_CHUNK * D_CH + d;
    float vre = 0.f, vim = 0.f;
#pragma unroll 8
    for (int k = 0; k < L_CHUNK; ++k) {
        float xv = xp[(size_t)k * D_CH];
        step_real(zre, zim, vre, vim, xv);
    }
    b[c * D_CH + d] = make_float2(vre, vim);
}

// Pass 2: per channel, exclusive scan over chunk summaries with z^L.
// In-place: b[c][d] is replaced by the carry INTO chunk c.
__global__ __launch_bounds__(256) void k_carry(const float* __restrict__ size_,
                                               const float* __restrict__ theta_,
                                               float2* __restrict__ b) {
    const int d = blockIdx.x * 256 + threadIdx.x;
    float e = expf(size_[d]);
    float th = theta_[d];
    // z^L = exp(-L*e) * (cos(L*th) + i sin(L*th))
    float rL = expf(-(float)L_CHUNK * e);      // underflow->0 is correct
    float sL, cL;
    sincosf((float)L_CHUNK * th, &sL, &cL);
    const float zLre = rL * cL, zLim = rL * sL;

    float cre = 0.f, cim = 0.f;
    for (int base = 0; base < C_CHUNKS; base += 16) {
        float2 loc[16];
#pragma unroll
        for (int j = 0; j < 16; ++j)
            loc[j] = b[(base + j) * D_CH + d];   // batch-issued, latency overlapped
#pragma unroll
        for (int j = 0; j < 16; ++j) {
            b[(base + j) * D_CH + d] = make_float2(cre, cim);
            // carry = z^L * carry + b_c   (b complex here)
            float nre = fmaf(zLre, cre, fmaf(-zLim, cim, loc[j].x));
            float nim = fmaf(zLre, cim, fmaf(zLim, cre, loc[j].y));
            cre = nre; cim = nim;
        }
    }
}

// Pass 3: re-run local scan seeded with the carry; write output.
template <bool INTERLEAVED>
__global__ __launch_bounds__(256) void k_final(const float* __restrict__ x,
                                               const float* __restrict__ size_,
                                               const float* __restrict__ theta_,
                                               const float2* __restrict__ carry,
                                               float* __restrict__ out) {
    const int d = blockIdx.x * 256 + threadIdx.x;
    const int c = blockIdx.y;
    float zre, zim;
    load_z(size_, theta_, d, zre, zim);

    float2 cv = carry[c * D_CH + d];
    float vre = cv.x, vim = cv.y;
    const float* xp = x + (size_t)c * L_CHUNK * D_CH + d;

    if (INTERLEAVED) {
        float2* outc = (float2*)out;
#pragma unroll 8
        for (int k = 0; k < L_CHUNK; ++k) {
            float xv = xp[(size_t)k * D_CH];
            step_real(zre, zim, vre, vim, xv);
            outc[(size_t)(c * L_CHUNK + k) * D_CH + d] = make_float2(vre, vim);
        }
    } else {
#pragma unroll 8
        for (int k = 0; k < L_CHUNK; ++k) {
            float xv = xp[(size_t)k * D_CH];
            step_real(zre, zim, vre, vim, xv);
            out[(size_t)(c * L_CHUNK + k) * D_CH + d] = vre;
        }
    }
}

extern "C" void kernel_launch(void* const* d_in, const int* in_sizes, int n_in,
                              void* d_out, int out_size, void* d_ws, size_t ws_size,
                              hipStream_t stream) {
    const float* x   = (const float*)d_in[0];
    const float* sz  = (const float*)d_in[1];
    const float* th  = (const float*)d_in[2];
    float2* b = (float2*)d_ws;   // C_CHUNKS * D_CH * 8 = 1 MB

    dim3 blk(256);
    dim3 grid1(D_CH / 256, C_CHUNKS);

    k_local<<<grid1, blk, 0, stream>>>(x, sz, th, b);
    k_carry<<<dim3(D_CH / 256), blk, 0, stream>>>(sz, th, b);

    if (out_size == T_LEN * D_CH) {
        // Harness stores real part only as float32 [T, D].
        k_final<false><<<grid1, blk, 0, stream>>>(x, sz, th, b, (float*)d_out);
    } else {
        // Full complex64 interleaved (re, im) pairs.
        k_final<true><<<grid1, blk, 0, stream>>>(x, sz, th, b, (float*)d_out);
    }
}